// Round 12
// baseline (23.706 us; speedup 1.0000x reference)
//
#include <hip/hip_runtime.h>

// X = prod_{i=0}^{n-1} (I + A_i/n), left-to-right, A: [N,2,2] f32 row-major.
// R11 post-mortem: NaN race — bl[] aliases wave0's segment-A floats and was
// written WITHOUT a barrier while wave0 could still be reading them (R9 had
// the barrier; R11 dropped it). R12: same counted-vmcnt A/B pipeline, with
// __syncthreads() BEFORE the bl writes (all tile reads done), then write,
// then barrier, then combine. Tail = R4's proven coalesced 2-kernel tree.

struct M2 { double a, b, c, d; };  // [[a,b],[c,d]]

__device__ __forceinline__ M2 m2mul(const M2& X, const M2& Y) {
    M2 r;
    r.a = fma(X.a, Y.a, X.b * Y.c);
    r.b = fma(X.a, Y.b, X.b * Y.d);
    r.c = fma(X.c, Y.a, X.d * Y.c);
    r.d = fma(X.c, Y.b, X.d * Y.d);
    return r;
}

__device__ __forceinline__ M2 from_f4(float4 v, double inv_n) {
    M2 M;
    M.a = fma((double)v.x, inv_n, 1.0);
    M.b = (double)v.y * inv_n;
    M.c = (double)v.z * inv_n;
    M.d = fma((double)v.w, inv_n, 1.0);
    return M;
}

// Ordered wave tree combine: lower lane = earlier chunk = left operand.
__device__ __forceinline__ M2 wave_combine(M2 P) {
    #pragma unroll
    for (int off = 1; off < 64; off <<= 1) {
        M2 Q;
        Q.a = __shfl_down(P.a, off);
        Q.b = __shfl_down(P.b, off);
        Q.c = __shfl_down(P.c, off);
        Q.d = __shfl_down(P.d, off);
        P = m2mul(P, Q);
    }
    return P;
}

__device__ __forceinline__ M2 load_m2(const double* p) {
    double2 lo = *reinterpret_cast<const double2*>(p);
    double2 hi = *reinterpret_cast<const double2*>(p + 2);
    M2 Q = { lo.x, lo.y, hi.x, hi.y };
    return Q;
}

__device__ __forceinline__ void store_m2(double* p, const M2& P) {
    *reinterpret_cast<double2*>(p)     = double2{ P.a, P.b };
    *reinterpret_cast<double2*>(p + 2) = double2{ P.c, P.d };
}

#define CHUNK 5
#define P1_TPB 256
#define SEG (64 * CHUNK)               // 320 matrices per wave-segment
#define TILE (SEG * 8)                 // 2560 matrices per block, 40 KB LDS

__global__ void __launch_bounds__(P1_TPB) prodchain_phase1(
    const float4* __restrict__ A, int n, double* __restrict__ part)
{
    __shared__ float4 tile[TILE];      // exactly 40 KB
    double* bl = (double*)tile;        // 4 wave partials; written only after
                                       // the pre-write __syncthreads below.

    const int tid = threadIdx.x;
    const int w = tid >> 6;
    const int l = tid & 63;
    const int blockStart = blockIdx.x * TILE;
    const int segA = blockStart + (2 * w) * SEG;     // wave's 1st segment
    const int segB = segA + SEG;                     // adjacent 2nd segment
    const double inv_n = 1.0 / (double)n;

    float4* la = &tile[(2 * w) * SEG];
    float4* lb = la + SEG;

    const bool full = (blockStart + TILE <= n);
    if (full) {
        // Pipelined direct HBM->LDS: A loads, then B loads, counted waits.
        const float4* ga = A + segA;
        const float4* gb = A + segB;
        #pragma unroll
        for (int k = 0; k < CHUNK; ++k)
            __builtin_amdgcn_global_load_lds(
                (const __attribute__((address_space(1))) void*)(ga + k * 64 + l),
                (__attribute__((address_space(3))) void*)(la + k * 64),
                16, 0, 0);
        #pragma unroll
        for (int k = 0; k < CHUNK; ++k)
            __builtin_amdgcn_global_load_lds(
                (const __attribute__((address_space(1))) void*)(gb + k * 64 + l),
                (__attribute__((address_space(3))) void*)(lb + k * 64),
                16, 0, 0);
        asm volatile("s_waitcnt vmcnt(5)" ::: "memory");   // A complete
    } else {
        // Guarded tail block: register staging, OOB -> 0 -> identity factor.
        #pragma unroll
        for (int k = 0; k < CHUNK; ++k) {
            int g = segA + k * 64 + l;
            la[k * 64 + l] = (g < n) ? A[g] : make_float4(0.f, 0.f, 0.f, 0.f);
        }
        #pragma unroll
        for (int k = 0; k < CHUNK; ++k) {
            int g = segB + k * 64 + l;
            lb[k * 64 + l] = (g < n) ? A[g] : make_float4(0.f, 0.f, 0.f, 0.f);
        }
        asm volatile("s_waitcnt lgkmcnt(0)" ::: "memory");
    }

    // Compute segment A (B's loads still in flight on the fast path).
    M2 P = {1.0, 0.0, 0.0, 1.0};
    {
        const float4* my = &la[l * CHUNK];
        #pragma unroll
        for (int j = 0; j < CHUNK; ++j)
            P = m2mul(P, from_f4(my[j], inv_n));
    }

    if (full) asm volatile("s_waitcnt vmcnt(0)" ::: "memory");  // B complete

    M2 Q = {1.0, 0.0, 0.0, 1.0};
    {
        const float4* my = &lb[l * CHUNK];
        #pragma unroll
        for (int j = 0; j < CHUNK; ++j)
            Q = m2mul(Q, from_f4(my[j], inv_n));
    }

    P = wave_combine(P);               // product of segment A
    Q = wave_combine(Q);               // product of segment B

    __syncthreads();                   // ALL tile reads done before aliasing
    if (l == 0) {
        M2 R = m2mul(P, Q);            // wave's contiguous 640-matrix product
        bl[4 * w + 0] = R.a;
        bl[4 * w + 1] = R.b;
        bl[4 * w + 2] = R.c;
        bl[4 * w + 3] = R.d;
    }
    __syncthreads();

    if (tid == 0) {
        M2 R = { bl[0], bl[1], bl[2], bl[3] };
        #pragma unroll
        for (int w2 = 1; w2 < 4; ++w2) {
            M2 T = { bl[4 * w2 + 0], bl[4 * w2 + 1],
                     bl[4 * w2 + 2], bl[4 * w2 + 3] };
            R = m2mul(R, T);
        }
        store_m2(&part[4 * blockIdx.x], R);
    }
}

// Lane-per-partial ordered reduce: block b combines partials [b*64, b*64+64)
// (identity for OOB) into out_part[b]. Coalesced 32B records.
__global__ void __launch_bounds__(64) prodchain_reduce(
    const double* __restrict__ in_part, int np, double* __restrict__ out_part)
{
    const int l = threadIdx.x;
    const int idx = blockIdx.x * 64 + l;
    M2 P = {1.0, 0.0, 0.0, 1.0};
    if (idx < np) P = load_m2(&in_part[4 * idx]);

    P = wave_combine(P);

    if (l == 0) store_m2(&out_part[4 * blockIdx.x], P);
}

__global__ void __launch_bounds__(64) prodchain_final(
    const double* __restrict__ in_part, int np, float* __restrict__ out)
{
    const int l = threadIdx.x;
    M2 P = {1.0, 0.0, 0.0, 1.0};
    if (l < np) P = load_m2(&in_part[4 * l]);

    P = wave_combine(P);

    if (l == 0) {
        out[0] = (float)P.a;
        out[1] = (float)P.b;
        out[2] = (float)P.c;
        out[3] = (float)P.d;
    }
}

extern "C" void kernel_launch(void* const* d_in, const int* in_sizes, int n_in,
                              void* d_out, int out_size, void* d_ws, size_t ws_size,
                              hipStream_t stream) {
    const float4* A = (const float4*)d_in[0];
    const int n = in_sizes[0] / 4;                    // 5,000,000 matrices
    const int nb1 = (n + TILE - 1) / TILE;            // 1954 block partials
    const int nb2 = (nb1 + 63) / 64;                  // 31 level-2 partials

    double* part1 = (double*)d_ws;                    // 1954 * 32 B = 62.5 KB
    double* part2 = part1 + 4 * 2048;                 // offset 64 KB

    prodchain_phase1<<<nb1, P1_TPB, 0, stream>>>(A, n, part1);
    prodchain_reduce<<<nb2, 64, 0, stream>>>(part1, nb1, part2);
    prodchain_final<<<1, 64, 0, stream>>>(part2, nb2, (float*)d_out);
}